// Round 8
// baseline (2965.298 us; speedup 1.0000x reference)
//
#include <hip/hip_runtime.h>
#include <hip/hip_fp16.h>
#include <hip/hip_cooperative_groups.h>

namespace cg = cooperative_groups;

#define Nn 50000
#define Ee 800000
#define Tt 12
#define NBAND 8
#define BAND 6250        // Nn / NBAND
#define NCH 16           // edge chunks for build
#define CHSZ 50000       // Ee / NCH
#define SCB 196          // scan blocks per dir: 196*256 >= Nn
#define NCHUNK2 1563     // ceil(Nn/32) node chunks for dense phase
// HID=128, K=3, F_IN=7, effective features = 35 (+1 bias slot)
// Node feature rows: 8 x f16 = 16 B (one dwordx4 gather).
// Adjacency entry: (src_node << 16) | half_bits(edge_weight) -- 4 bytes.

// ======== pass1: per-(chunk,band) LDS histogram -> cntCh (no atomics) ======
__global__ __launch_bounds__(256) void pass1_kernel(
    const int* __restrict__ ei, int* __restrict__ cntCh)
{
    __shared__ int hR[BAND], hC[BAND];
    int j = blockIdx.x >> 3;        // chunk
    int b = blockIdx.x & 7;         // band
    int lo = b * BAND;
    for (int i = threadIdx.x; i < BAND; i += 256) { hR[i] = 0; hC[i] = 0; }
    __syncthreads();
    int e0 = j * CHSZ;
    for (int e = e0 + threadIdx.x; e < e0 + CHSZ; e += 256) {
        int r = __builtin_nontemporal_load(ei + e);
        int c = __builtin_nontemporal_load(ei + Ee + e);
        if ((unsigned)(r - lo) < BAND) atomicAdd(&hR[r - lo], 1);
        if ((unsigned)(c - lo) < BAND) atomicAdd(&hC[c - lo], 1);
    }
    __syncthreads();
    for (int i = threadIdx.x; i < BAND; i += 256) {
        cntCh[(0 * NCH + j) * Nn + lo + i] = hR[i];
        cntCh[(1 * NCH + j) * Nn + lo + i] = hC[i];
    }
}

// ---- 3-phase scan: tot per node (sum over chunks) + exclusive node scan ---
__global__ __launch_bounds__(256) void scanA_kernel(
    const int* __restrict__ cntCh, int* __restrict__ tot, int* __restrict__ bsum)
{
    int y = blockIdx.y;
    int i = blockIdx.x * 256 + threadIdx.x;
    int v = 0;
    if (i < Nn) {
        #pragma unroll
        for (int j = 0; j < NCH; j++) v += cntCh[(y * NCH + j) * Nn + i];
        tot[y * Nn + i] = v;
    }
    __shared__ int ws_[4];
    int s = v;
    s += __shfl_xor(s, 1);  s += __shfl_xor(s, 2);  s += __shfl_xor(s, 4);
    s += __shfl_xor(s, 8);  s += __shfl_xor(s, 16); s += __shfl_xor(s, 32);
    if ((threadIdx.x & 63) == 0) ws_[threadIdx.x >> 6] = s;
    __syncthreads();
    if (threadIdx.x == 0)
        bsum[y * 256 + blockIdx.x] = ws_[0] + ws_[1] + ws_[2] + ws_[3];
}

__global__ __launch_bounds__(256) void scanB_kernel(
    const int* __restrict__ bsum, int* __restrict__ bbase)
{
    int y = blockIdx.x;
    __shared__ int s[256];
    int t = threadIdx.x;
    int v = (t < SCB) ? bsum[y * 256 + t] : 0;
    s[t] = v;
    __syncthreads();
    for (int off = 1; off < 256; off <<= 1) {
        int u = (t >= off) ? s[t - off] : 0;
        __syncthreads();
        s[t] += u;
        __syncthreads();
    }
    bbase[y * 256 + t] = s[t] - v;   // exclusive
}

__global__ __launch_bounds__(256) void scanC_kernel(
    const int* __restrict__ tot, const int* __restrict__ bbase,
    int* __restrict__ start)
{
    int y = blockIdx.y;
    int i = blockIdx.x * 256 + threadIdx.x;
    int v = (i < Nn) ? tot[y * Nn + i] : 0;
    __shared__ int s[256];
    int t = threadIdx.x;
    s[t] = v;
    __syncthreads();
    for (int off = 1; off < 256; off <<= 1) {
        int u = (t >= off) ? s[t - off] : 0;
        __syncthreads();
        s[t] += u;
        __syncthreads();
    }
    if (i < Nn) start[y * Nn + i] = bbase[y * 256 + blockIdx.x] + s[t] - v;
}

// ======== pass2: scatter with LDS cursors (on-CU atomics only) =============
__global__ __launch_bounds__(256) void pass2_kernel(
    const int* __restrict__ ei, const float* __restrict__ ew,
    const int* __restrict__ cntCh, const int* __restrict__ start,
    unsigned* __restrict__ adjR, unsigned* __restrict__ adjC)
{
    __shared__ int curR[BAND], curC[BAND];
    int j = blockIdx.x >> 3;
    int b = blockIdx.x & 7;
    int lo = b * BAND;
    for (int i = threadIdx.x; i < BAND; i += 256) {
        int sR = start[lo + i];
        int sC = start[Nn + lo + i];
        for (int jj = 0; jj < j; jj++) {
            sR += cntCh[(0 * NCH + jj) * Nn + lo + i];
            sC += cntCh[(1 * NCH + jj) * Nn + lo + i];
        }
        curR[i] = sR; curC[i] = sC;
    }
    __syncthreads();
    int e0 = j * CHSZ;
    for (int e = e0 + threadIdx.x; e < e0 + CHSZ; e += 256) {
        int r = __builtin_nontemporal_load(ei + e);
        int c = __builtin_nontemporal_load(ei + Ee + e);
        float wf = __builtin_nontemporal_load(ew + e);
        unsigned wb = __half_as_ushort(__float2half(wf));
        if ((unsigned)(r - lo) < BAND) {
            int slot = atomicAdd(&curR[r - lo], 1);
            adjR[slot] = ((unsigned)c << 16) | wb;
        }
        if ((unsigned)(c - lo) < BAND) {
            int slot = atomicAdd(&curC[c - lo], 1);
            adjC[slot] = ((unsigned)r << 16) | wb;
        }
    }
}

// ==== effective weights, layout [gate][k*128 + j], k=35 is the bias row ====
// f layout: [0..6]=X, [7..13]=Tx_o, [14..20]=Tx_i, [21..27]=T2_o, [28..34]=T2_i, [35]=1
__global__ __launch_bounds__(256) void weff_kernel(
    const float* __restrict__ Wz, const float* __restrict__ Wh,
    const float* __restrict__ bz, const float* __restrict__ bh,
    float* __restrict__ wzT, float* __restrict__ whT)
{
    int idx = blockIdx.x * 256 + threadIdx.x;
    if (idx >= 2 * 36 * 128) return;
    const float* W = (idx < 36 * 128) ? Wz : Wh;
    const float* B = (idx < 36 * 128) ? bz : bh;
    float* O       = (idx < 36 * 128) ? wzT : whT;
    int rem = idx % (36 * 128);
    int k = rem / 128, j = rem % 128;
    float v;
    if (k == 35) v = B[j];
    else {
        int p = k / 7, rr = k % 7;
        if (p == 0)      v = W[(0 * 135 + rr) * 128 + j] + W[(3 * 135 + rr) * 128 + j];
        else if (p == 1) v = W[(1 * 135 + rr) * 128 + j];
        else if (p == 2) v = W[(4 * 135 + rr) * 128 + j];
        else if (p == 3) v = W[(2 * 135 + rr) * 128 + j];
        else             v = W[(5 * 135 + rr) * 128 + j];
    }
    O[k * 128 + j] = v;
}

// =================== init: Xh row (f16) and out column 0 ===================
__global__ __launch_bounds__(256) void init_kernel(
    const float* __restrict__ x, const float* __restrict__ env,
    const float* __restrict__ coords, __half* __restrict__ Xh,
    float* __restrict__ out)
{
    int i = blockIdx.x * 256 + threadIdx.x;
    if (i >= Nn) return;
    float xv = x[i * Tt];
    __half* r = Xh + (long)i * 8;
    r[0] = __float2half(xv);
    #pragma unroll
    for (int c = 0; c < 4; c++) r[1 + c] = __float2half(env[i * 48 + c * 12]);
    r[5] = __float2half(coords[i * 2 + 0]);
    r[6] = __float2half(coords[i * 2 + 1]);
    r[7] = __half(0.f);
    out[i * 13 + 0] = xv;
}

__device__ __forceinline__ void unpack8(const __half* p, float* v) {
    uint4 hv = *((const uint4*)p);
    float2 p0 = __half22float2(*(__half2*)&hv.x);
    float2 p1 = __half22float2(*(__half2*)&hv.y);
    float2 p2 = __half22float2(*(__half2*)&hv.z);
    float2 p3 = __half22float2(*(__half2*)&hv.w);
    v[0] = p0.x; v[1] = p0.y; v[2] = p1.x; v[3] = p1.y;
    v[4] = p2.x; v[5] = p2.y; v[6] = p3.x;
}

__device__ __forceinline__ void pack8(__half* p, const float* v) {
    __half2 q0 = __floats2half2_rn(v[0], v[1]);
    __half2 q1 = __floats2half2_rn(v[2], v[3]);
    __half2 q2 = __floats2half2_rn(v[4], v[5]);
    __half2 q3 = __floats2half2_rn(v[6], 0.f);
    uint4 st;
    st.x = *(unsigned*)&q0; st.y = *(unsigned*)&q1;
    st.z = *(unsigned*)&q2; st.w = *(unsigned*)&q3;
    *((uint4*)p) = st;
}

__device__ __forceinline__ void acc7(float* a, float w, uint4 hv) {
    float2 p0 = __half22float2(*(__half2*)&hv.x);
    float2 p1 = __half22float2(*(__half2*)&hv.y);
    float2 p2 = __half22float2(*(__half2*)&hv.z);
    float2 p3 = __half22float2(*(__half2*)&hv.w);
    a[0] = fmaf(w, p0.x, a[0]); a[1] = fmaf(w, p0.y, a[1]);
    a[2] = fmaf(w, p1.x, a[2]); a[3] = fmaf(w, p1.y, a[3]);
    a[4] = fmaf(w, p2.x, a[4]); a[5] = fmaf(w, p2.y, a[5]);
    a[6] = fmaf(w, p3.x, a[6]);
}

__device__ __forceinline__ float wdec(unsigned ed) {
    return __half2float(__ushort_as_half((unsigned short)(ed & 0xffffu)));
}

// ======= cooperative persistent kernel: all 12 timesteps, 1 dispatch =======
// Per step: phase1 = first-order gather (Tx), grid.sync, phase2 = fused
// second-order gather + dense contraction + output, grid.sync.
__global__ __launch_bounds__(256) void loop_kernel(
    const int* __restrict__ startR, const int* __restrict__ totR,
    const unsigned* __restrict__ adjR,
    const int* __restrict__ startC, const int* __restrict__ totC,
    const unsigned* __restrict__ adjC,
    float* __restrict__ inv_out, float* __restrict__ inv_in,
    const float* __restrict__ env, const float* __restrict__ night,
    const float* __restrict__ wzT, const float* __restrict__ whT,
    const float* __restrict__ linW, const float* __restrict__ linb,
    __half* __restrict__ Xh, __half* __restrict__ TxoH, __half* __restrict__ TxiH,
    float* __restrict__ out)
{
    cg::grid_group grid = cg::this_grid();
    __shared__ float f_s[32][36];
    __shared__ float part_s[2][32];
    int tid = threadIdx.x;
    int lane = tid & 63;
    int wave = tid >> 6;
    int chSel = wave & 1;
    int ch = chSel * 64 + lane;
    int half_id = wave >> 1;
    int gsz = gridDim.x * 256;

    // channel-resident weights (loop-invariant across all steps)
    float wz[36], wh[36];
    #pragma unroll
    for (int k = 0; k < 36; k++) wz[k] = wzT[k * 128 + ch];
    #pragma unroll
    for (int k = 0; k < 36; k++) wh[k] = whT[k * 128 + ch];
    float lw = linW[ch];
    float lb = linb[0];

    for (int t = 0; t < Tt; t++) {
        // ---------------- phase 1: Tx = inv * segsum(w * Xh[src]) ----------
        for (int task = blockIdx.x * 256 + tid; task < Nn * 8; task += gsz) {
            int node = task >> 3;
            int dir = (task >> 2) & 1, sub = task & 3;
            const int*      st  = dir ? startC : startR;
            const int*      to  = dir ? totC : totR;
            const unsigned* adj = dir ? adjC : adjR;
            int b = st[node], e = b + to[node];
            float a[7] = {0.f, 0.f, 0.f, 0.f, 0.f, 0.f, 0.f};
            float sw = 0.f;
            int k = b + sub;
            for (; k + 12 < e; k += 16) {
                unsigned e0 = __builtin_nontemporal_load(adj + k);
                unsigned e1 = __builtin_nontemporal_load(adj + k + 4);
                unsigned e2 = __builtin_nontemporal_load(adj + k + 8);
                unsigned e3 = __builtin_nontemporal_load(adj + k + 12);
                uint4 r0 = *(const uint4*)(Xh + (long)(e0 >> 16) * 8);
                uint4 r1 = *(const uint4*)(Xh + (long)(e1 >> 16) * 8);
                uint4 r2 = *(const uint4*)(Xh + (long)(e2 >> 16) * 8);
                uint4 r3 = *(const uint4*)(Xh + (long)(e3 >> 16) * 8);
                float w0 = wdec(e0), w1 = wdec(e1), w2 = wdec(e2), w3 = wdec(e3);
                acc7(a, w0, r0); acc7(a, w1, r1); acc7(a, w2, r2); acc7(a, w3, r3);
                sw += (w0 + w1) + (w2 + w3);
            }
            for (; k < e; k += 4) {
                unsigned ed = __builtin_nontemporal_load(adj + k);
                uint4 rv = *(const uint4*)(Xh + (long)(ed >> 16) * 8);
                float w = wdec(ed);
                acc7(a, w, rv);
                sw += w;
            }
            #pragma unroll
            for (int m = 1; m <= 2; m <<= 1) {
                #pragma unroll
                for (int q = 0; q < 7; q++) a[q] += __shfl_xor(a[q], m);
                sw += __shfl_xor(sw, m);
            }
            if (sub == 0) {
                float inv = sw > 0.f ? 1.f / sw : 0.f;
                (dir ? inv_in : inv_out)[node] = inv;
                #pragma unroll
                for (int q = 0; q < 7; q++) a[q] *= inv;
                pack8((dir ? TxiH : TxoH) + (long)node * 8, a);
            }
        }
        __threadfence();
        grid.sync();

        // -------- phase 2: T2 gather (LDS) + dense + output + next X -------
        for (int chunk = blockIdx.x; chunk < NCHUNK2; chunk += gridDim.x) {
            int base = chunk * 32;
            {   // A: second-order propagation straight into LDS (fp32)
                int nl = tid >> 3;
                int dir = (tid >> 2) & 1, sub = tid & 3;
                int node = base + nl;
                int nc = node < Nn ? node : Nn - 1;
                const int*      st  = dir ? startC : startR;
                const int*      to  = dir ? totC : totR;
                const unsigned* adj = dir ? adjC : adjR;
                const __half*   src = dir ? TxiH : TxoH;
                int b = st[nc], e = b + to[nc];
                float a[7] = {0.f, 0.f, 0.f, 0.f, 0.f, 0.f, 0.f};
                int k = b + sub;
                for (; k + 12 < e; k += 16) {
                    unsigned e0 = __builtin_nontemporal_load(adj + k);
                    unsigned e1 = __builtin_nontemporal_load(adj + k + 4);
                    unsigned e2 = __builtin_nontemporal_load(adj + k + 8);
                    unsigned e3 = __builtin_nontemporal_load(adj + k + 12);
                    uint4 r0 = *(const uint4*)(src + (long)(e0 >> 16) * 8);
                    uint4 r1 = *(const uint4*)(src + (long)(e1 >> 16) * 8);
                    uint4 r2 = *(const uint4*)(src + (long)(e2 >> 16) * 8);
                    uint4 r3 = *(const uint4*)(src + (long)(e3 >> 16) * 8);
                    float w0 = wdec(e0), w1 = wdec(e1), w2 = wdec(e2), w3 = wdec(e3);
                    acc7(a, w0, r0); acc7(a, w1, r1); acc7(a, w2, r2); acc7(a, w3, r3);
                }
                for (; k < e; k += 4) {
                    unsigned ed = __builtin_nontemporal_load(adj + k);
                    uint4 rv = *(const uint4*)(src + (long)(ed >> 16) * 8);
                    acc7(a, wdec(ed), rv);
                }
                #pragma unroll
                for (int m = 1; m <= 2; m <<= 1) {
                    #pragma unroll
                    for (int q = 0; q < 7; q++) a[q] += __shfl_xor(a[q], m);
                }
                if (sub == 0) {
                    float s2 = 2.f * (dir ? inv_in[nc] : inv_out[nc]);
                    float xv[7], tx[7];
                    unpack8(Xh + (long)nc * 8, xv);
                    unpack8(src + (long)nc * 8, tx);
                    #pragma unroll
                    for (int q = 0; q < 7; q++) {
                        f_s[nl][21 + 7 * dir + q] = fmaf(s2, a[q], -xv[q]);
                        f_s[nl][7 + 7 * dir + q]  = tx[q];
                    }
                    if (dir == 0) {
                        #pragma unroll
                        for (int q = 0; q < 7; q++) f_s[nl][q] = xv[q];
                        f_s[nl][35] = 1.f;
                    }
                }
            }
            __syncthreads();
            // B: dense 36x128x2 contraction + activations
            #pragma unroll 1
            for (int n = 0; n < 16; n++) {
                int ni = half_id * 16 + n;
                const float4* fv = (const float4*)f_s[ni];
                float hz = 0.f, hh = 0.f;
                #pragma unroll
                for (int q = 0; q < 9; q++) {
                    float4 fq = fv[q];
                    hz = fmaf(fq.x, wz[q*4+0], hz); hh = fmaf(fq.x, wh[q*4+0], hh);
                    hz = fmaf(fq.y, wz[q*4+1], hz); hh = fmaf(fq.y, wh[q*4+1], hh);
                    hz = fmaf(fq.z, wz[q*4+2], hz); hh = fmaf(fq.z, wh[q*4+2], hh);
                    hz = fmaf(fq.w, wz[q*4+3], hz); hh = fmaf(fq.w, wh[q*4+3], hh);
                }
                float z  = 1.f / (1.f + __expf(-hz));
                float e2 = __expf(2.f * hh);
                float ht = 1.f - 2.f / (e2 + 1.f);
                float v = fmaxf((1.f - z) * ht, 0.f) * lw;
                v += __shfl_xor(v, 1);  v += __shfl_xor(v, 2);  v += __shfl_xor(v, 4);
                v += __shfl_xor(v, 8);  v += __shfl_xor(v, 16); v += __shfl_xor(v, 32);
                if (lane == 0) part_s[chSel][ni] = v;
            }
            __syncthreads();
            if (tid < 32) {
                int node = base + tid;
                if (node < Nn) {
                    float o = part_s[0][tid] + part_s[1][tid] + lb;
                    o *= night[(long)node * 13 + t + 1];
                    out[(long)node * 13 + t + 1] = o;
                    if (t + 1 < Tt) {
                        __half* xr = Xh + (long)node * 8;
                        xr[0] = __float2half(o);
                        #pragma unroll
                        for (int c = 0; c < 4; c++)
                            xr[1 + c] = __float2half(env[(long)node * 48 + c * 12 + t + 1]);
                    }
                }
            }
            __syncthreads();
        }
        __threadfence();
        grid.sync();
    }
}

extern "C" void kernel_launch(void* const* d_in, const int* in_sizes, int n_in,
                              void* d_out, int out_size, void* d_ws, size_t ws_size,
                              hipStream_t stream) {
    const float* x      = (const float*)d_in[0];
    const float* env    = (const float*)d_in[1];
    const float* coords = (const float*)d_in[2];
    const int*   ei     = (const int*)d_in[3];
    const float* ew     = (const float*)d_in[4];
    const float* night  = (const float*)d_in[5];
    const float* Wz     = (const float*)d_in[6];
    const float* bz     = (const float*)d_in[7];
    // d_in[8]=Wr, d_in[9]=br unused (R gate never affects output)
    const float* Wh     = (const float*)d_in[10];
    const float* bh     = (const float*)d_in[11];
    const float* linW   = (const float*)d_in[12];
    const float* linb   = (const float*)d_in[13];
    float* out = (float*)d_out;

    float* w = (float*)d_ws;
    float* wzT     = w;                     // 36*128
    float* whT     = w + 4608;
    float* inv_out = w + 9216;              // N
    float* inv_in  = w + 59216;
    __half* Xh   = (__half*)(w + 109216);   // N x 8 halves
    __half* TxoH = (__half*)(w + 309216);
    __half* TxiH = (__half*)(w + 509216);
    int* ibase   = (int*)(w + 709216);
    int* tot     = ibase;                   // 2 x N   (totR | totC)
    int* start   = ibase + 100000;          // 2 x N
    int* cntCh   = ibase + 200000;          // 2 x 16 x N
    int* bsum    = ibase + 1800000;         // 2 x 256
    int* bbase   = ibase + 1800512;
    unsigned* adjR = (unsigned*)(ibase + 1801024);   // E x 4B
    unsigned* adjC = adjR + Ee;

    // ---- atomic-free CSR build ----
    pass1_kernel<<<NCH * NBAND, 256, 0, stream>>>(ei, cntCh);
    scanA_kernel<<<dim3(SCB, 2), 256, 0, stream>>>(cntCh, tot, bsum);
    scanB_kernel<<<2, 256, 0, stream>>>(bsum, bbase);
    scanC_kernel<<<dim3(SCB, 2), 256, 0, stream>>>(tot, bbase, start);
    pass2_kernel<<<NCH * NBAND, 256, 0, stream>>>(ei, ew, cntCh, start, adjR, adjC);

    weff_kernel<<<(2 * 36 * 128 + 255) / 256, 256, 0, stream>>>(Wz, Wh, bz, bh, wzT, whT);
    init_kernel<<<(Nn + 255) / 256, 256, 0, stream>>>(x, env, coords, Xh, out);

    // ---- cooperative persistent loop kernel (all 12 steps) ----
    int nb = 0;
    hipError_t oe = hipOccupancyMaxActiveBlocksPerMultiprocessor(&nb, loop_kernel, 256, 0);
    if (oe != hipSuccess || nb < 1) nb = 2;
    int G = nb * 256;                 // 256 CUs on MI355X
    if (G > NCHUNK2) G = NCHUNK2;

    const int* startR = start;
    const int* startC = start + Nn;
    const int* totR   = tot;
    const int* totC   = tot + Nn;
    void* kargs[] = {
        (void*)&startR, (void*)&totR, (void*)&adjR,
        (void*)&startC, (void*)&totC, (void*)&adjC,
        (void*)&inv_out, (void*)&inv_in,
        (void*)&env, (void*)&night,
        (void*)&wzT, (void*)&whT, (void*)&linW, (void*)&linb,
        (void*)&Xh, (void*)&TxoH, (void*)&TxiH, (void*)&out };
    hipLaunchCooperativeKernel(loop_kernel, dim3(G), dim3(256), kargs, 0, stream);
}

// Round 9
// 1001.239 us; speedup vs baseline: 2.9616x; 2.9616x over previous
//
#include <hip/hip_runtime.h>
#include <hip/hip_fp16.h>

#define Nn 50000
#define Ee 800000
#define Tt 12
#define NBAND 8
#define BAND 6250        // Nn / NBAND
#define NCH 16           // edge chunks for build
#define CHSZ 50000       // Ee / NCH
#define SCB 196          // scan blocks per dir: 196*256 >= Nn
// HID=128, K=3, F_IN=7, effective features = 35 (+1 bias slot)
// Node feature rows: 8 x f16 = 16 B (one dwordx4 gather).
// Adjacency entry: (src_node << 16) | half_bits(edge_weight) -- 4 bytes.

// ======== pass1: per-(chunk,band) LDS histogram -> cntCh (no atomics) ======
__global__ __launch_bounds__(256) void pass1_kernel(
    const int* __restrict__ ei, int* __restrict__ cntCh)
{
    __shared__ int hR[BAND], hC[BAND];
    int j = blockIdx.x >> 3;        // chunk
    int b = blockIdx.x & 7;         // band
    int lo = b * BAND;
    for (int i = threadIdx.x; i < BAND; i += 256) { hR[i] = 0; hC[i] = 0; }
    __syncthreads();
    int e0 = j * CHSZ;
    for (int e = e0 + threadIdx.x; e < e0 + CHSZ; e += 256) {
        int r = __builtin_nontemporal_load(ei + e);
        int c = __builtin_nontemporal_load(ei + Ee + e);
        if ((unsigned)(r - lo) < BAND) atomicAdd(&hR[r - lo], 1);
        if ((unsigned)(c - lo) < BAND) atomicAdd(&hC[c - lo], 1);
    }
    __syncthreads();
    for (int i = threadIdx.x; i < BAND; i += 256) {
        cntCh[(0 * NCH + j) * Nn + lo + i] = hR[i];
        cntCh[(1 * NCH + j) * Nn + lo + i] = hC[i];
    }
}

// ---- 3-phase scan: tot per node (sum over chunks) + exclusive node scan ---
__global__ __launch_bounds__(256) void scanA_kernel(
    const int* __restrict__ cntCh, int* __restrict__ tot, int* __restrict__ bsum)
{
    int y = blockIdx.y;
    int i = blockIdx.x * 256 + threadIdx.x;
    int v = 0;
    if (i < Nn) {
        #pragma unroll
        for (int j = 0; j < NCH; j++) v += cntCh[(y * NCH + j) * Nn + i];
        tot[y * Nn + i] = v;
    }
    __shared__ int ws_[4];
    int s = v;
    s += __shfl_xor(s, 1);  s += __shfl_xor(s, 2);  s += __shfl_xor(s, 4);
    s += __shfl_xor(s, 8);  s += __shfl_xor(s, 16); s += __shfl_xor(s, 32);
    if ((threadIdx.x & 63) == 0) ws_[threadIdx.x >> 6] = s;
    __syncthreads();
    if (threadIdx.x == 0)
        bsum[y * 256 + blockIdx.x] = ws_[0] + ws_[1] + ws_[2] + ws_[3];
}

__global__ __launch_bounds__(256) void scanB_kernel(
    const int* __restrict__ bsum, int* __restrict__ bbase)
{
    int y = blockIdx.x;
    __shared__ int s[256];
    int t = threadIdx.x;
    int v = (t < SCB) ? bsum[y * 256 + t] : 0;
    s[t] = v;
    __syncthreads();
    for (int off = 1; off < 256; off <<= 1) {
        int u = (t >= off) ? s[t - off] : 0;
        __syncthreads();
        s[t] += u;
        __syncthreads();
    }
    bbase[y * 256 + t] = s[t] - v;   // exclusive
}

__global__ __launch_bounds__(256) void scanC_kernel(
    const int* __restrict__ tot, const int* __restrict__ bbase,
    int* __restrict__ start)
{
    int y = blockIdx.y;
    int i = blockIdx.x * 256 + threadIdx.x;
    int v = (i < Nn) ? tot[y * Nn + i] : 0;
    __shared__ int s[256];
    int t = threadIdx.x;
    s[t] = v;
    __syncthreads();
    for (int off = 1; off < 256; off <<= 1) {
        int u = (t >= off) ? s[t - off] : 0;
        __syncthreads();
        s[t] += u;
        __syncthreads();
    }
    if (i < Nn) start[y * Nn + i] = bbase[y * 256 + blockIdx.x] + s[t] - v;
}

// ======== pass2: scatter with LDS cursors (on-CU atomics only) =============
__global__ __launch_bounds__(256) void pass2_kernel(
    const int* __restrict__ ei, const float* __restrict__ ew,
    const int* __restrict__ cntCh, const int* __restrict__ start,
    unsigned* __restrict__ adjR, unsigned* __restrict__ adjC)
{
    __shared__ int curR[BAND], curC[BAND];
    int j = blockIdx.x >> 3;
    int b = blockIdx.x & 7;
    int lo = b * BAND;
    for (int i = threadIdx.x; i < BAND; i += 256) {
        int sR = start[lo + i];
        int sC = start[Nn + lo + i];
        for (int jj = 0; jj < j; jj++) {
            sR += cntCh[(0 * NCH + jj) * Nn + lo + i];
            sC += cntCh[(1 * NCH + jj) * Nn + lo + i];
        }
        curR[i] = sR; curC[i] = sC;
    }
    __syncthreads();
    int e0 = j * CHSZ;
    for (int e = e0 + threadIdx.x; e < e0 + CHSZ; e += 256) {
        int r = __builtin_nontemporal_load(ei + e);
        int c = __builtin_nontemporal_load(ei + Ee + e);
        float wf = __builtin_nontemporal_load(ew + e);
        unsigned wb = __half_as_ushort(__float2half(wf));
        if ((unsigned)(r - lo) < BAND) {
            int slot = atomicAdd(&curR[r - lo], 1);
            adjR[slot] = ((unsigned)c << 16) | wb;
        }
        if ((unsigned)(c - lo) < BAND) {
            int slot = atomicAdd(&curC[c - lo], 1);
            adjC[slot] = ((unsigned)r << 16) | wb;
        }
    }
}

// ==== effective weights, layout [gate][k*128 + j], k=35 is the bias row ====
// f layout: [0..6]=X, [7..13]=Tx_o, [14..20]=Tx_i, [21..27]=T2_o, [28..34]=T2_i, [35]=1
__global__ __launch_bounds__(256) void weff_kernel(
    const float* __restrict__ Wz, const float* __restrict__ Wh,
    const float* __restrict__ bz, const float* __restrict__ bh,
    float* __restrict__ wzT, float* __restrict__ whT)
{
    int idx = blockIdx.x * 256 + threadIdx.x;
    if (idx >= 2 * 36 * 128) return;
    const float* W = (idx < 36 * 128) ? Wz : Wh;
    const float* B = (idx < 36 * 128) ? bz : bh;
    float* O       = (idx < 36 * 128) ? wzT : whT;
    int rem = idx % (36 * 128);
    int k = rem / 128, j = rem % 128;
    float v;
    if (k == 35) v = B[j];
    else {
        int p = k / 7, rr = k % 7;
        if (p == 0)      v = W[(0 * 135 + rr) * 128 + j] + W[(3 * 135 + rr) * 128 + j];
        else if (p == 1) v = W[(1 * 135 + rr) * 128 + j];
        else if (p == 2) v = W[(4 * 135 + rr) * 128 + j];
        else if (p == 3) v = W[(2 * 135 + rr) * 128 + j];
        else             v = W[(5 * 135 + rr) * 128 + j];
    }
    O[k * 128 + j] = v;
}

// =================== init: Xh row (f16) and out column 0 ===================
__global__ __launch_bounds__(256) void init_kernel(
    const float* __restrict__ x, const float* __restrict__ env,
    const float* __restrict__ coords, __half* __restrict__ Xh,
    float* __restrict__ out)
{
    int i = blockIdx.x * 256 + threadIdx.x;
    if (i >= Nn) return;
    float xv = x[i * Tt];
    __half* r = Xh + (long)i * 8;
    r[0] = __float2half(xv);
    #pragma unroll
    for (int c = 0; c < 4; c++) r[1 + c] = __float2half(env[i * 48 + c * 12]);
    r[5] = __float2half(coords[i * 2 + 0]);
    r[6] = __float2half(coords[i * 2 + 1]);
    r[7] = __half(0.f);
    out[i * 13 + 0] = xv;
}

__device__ __forceinline__ void unpack8(const __half* p, float* v) {
    uint4 hv = *((const uint4*)p);
    float2 p0 = __half22float2(*(__half2*)&hv.x);
    float2 p1 = __half22float2(*(__half2*)&hv.y);
    float2 p2 = __half22float2(*(__half2*)&hv.z);
    float2 p3 = __half22float2(*(__half2*)&hv.w);
    v[0] = p0.x; v[1] = p0.y; v[2] = p1.x; v[3] = p1.y;
    v[4] = p2.x; v[5] = p2.y; v[6] = p3.x;
}

__device__ __forceinline__ void pack8(__half* p, const float* v) {
    __half2 q0 = __floats2half2_rn(v[0], v[1]);
    __half2 q1 = __floats2half2_rn(v[2], v[3]);
    __half2 q2 = __floats2half2_rn(v[4], v[5]);
    __half2 q3 = __floats2half2_rn(v[6], 0.f);
    uint4 st;
    st.x = *(unsigned*)&q0; st.y = *(unsigned*)&q1;
    st.z = *(unsigned*)&q2; st.w = *(unsigned*)&q3;
    *((uint4*)p) = st;
}

__device__ __forceinline__ void acc7(float* a, float w, uint4 hv) {
    float2 p0 = __half22float2(*(__half2*)&hv.x);
    float2 p1 = __half22float2(*(__half2*)&hv.y);
    float2 p2 = __half22float2(*(__half2*)&hv.z);
    float2 p3 = __half22float2(*(__half2*)&hv.w);
    a[0] = fmaf(w, p0.x, a[0]); a[1] = fmaf(w, p0.y, a[1]);
    a[2] = fmaf(w, p1.x, a[2]); a[3] = fmaf(w, p1.y, a[3]);
    a[4] = fmaf(w, p2.x, a[4]); a[5] = fmaf(w, p2.y, a[5]);
    a[6] = fmaf(w, p3.x, a[6]);
}

__device__ __forceinline__ float wdec(unsigned ed) {
    return __half2float(__ushort_as_half((unsigned short)(ed & 0xffffu)));
}

// ============== gather pass 1: Tx = inv * segsum(w * Xh[src]) ==============
// 8 threads per node: bit2 = dir (out/in), bits0-1 = sub. Inner loop batches
// 4 strided adj entries -> 4 independent 16B gathers in flight.
__global__ __launch_bounds__(256) void gather1_kernel(
    const int* __restrict__ startR, const int* __restrict__ totR,
    const unsigned* __restrict__ adjR,
    const int* __restrict__ startC, const int* __restrict__ totC,
    const unsigned* __restrict__ adjC,
    const __half* __restrict__ Xh,
    __half* __restrict__ TxoH, __half* __restrict__ TxiH,
    float* __restrict__ inv_out, float* __restrict__ inv_in)
{
    int tid = blockIdx.x * 256 + threadIdx.x;
    if (tid >= Nn * 8) return;
    int node = tid >> 3;
    int dir = (tid >> 2) & 1, sub = tid & 3;
    const int*      st  = dir ? startC : startR;
    const int*      to  = dir ? totC : totR;
    const unsigned* adj = dir ? adjC : adjR;
    int b = st[node], e = b + to[node];
    float a[7] = {0.f, 0.f, 0.f, 0.f, 0.f, 0.f, 0.f};
    float sw = 0.f;
    int k = b + sub;
    for (; k + 12 < e; k += 16) {
        unsigned e0 = adj[k], e1 = adj[k + 4], e2 = adj[k + 8], e3 = adj[k + 12];
        uint4 r0 = *(const uint4*)(Xh + (long)(e0 >> 16) * 8);
        uint4 r1 = *(const uint4*)(Xh + (long)(e1 >> 16) * 8);
        uint4 r2 = *(const uint4*)(Xh + (long)(e2 >> 16) * 8);
        uint4 r3 = *(const uint4*)(Xh + (long)(e3 >> 16) * 8);
        float w0 = wdec(e0), w1 = wdec(e1), w2 = wdec(e2), w3 = wdec(e3);
        acc7(a, w0, r0); acc7(a, w1, r1); acc7(a, w2, r2); acc7(a, w3, r3);
        sw += (w0 + w1) + (w2 + w3);
    }
    for (; k < e; k += 4) {
        unsigned ed = adj[k];
        uint4 rv = *(const uint4*)(Xh + (long)(ed >> 16) * 8);
        float w = wdec(ed);
        acc7(a, w, rv);
        sw += w;
    }
    #pragma unroll
    for (int m = 1; m <= 2; m <<= 1) {
        #pragma unroll
        for (int q = 0; q < 7; q++) a[q] += __shfl_xor(a[q], m);
        sw += __shfl_xor(sw, m);
    }
    if (sub == 0) {
        float inv = sw > 0.f ? 1.f / sw : 0.f;
        (dir ? inv_in : inv_out)[node] = inv;
        #pragma unroll
        for (int q = 0; q < 7; q++) a[q] *= inv;
        pack8((dir ? TxiH : TxoH) + (long)node * 8, a);
    }
}

// ====== fused step2: second-order propagation (into LDS, fp32) + dense =====
__global__ __launch_bounds__(256) void step2_kernel(
    const int* __restrict__ startR, const int* __restrict__ totR,
    const unsigned* __restrict__ adjR,
    const int* __restrict__ startC, const int* __restrict__ totC,
    const unsigned* __restrict__ adjC,
    const float* __restrict__ inv_out, const float* __restrict__ inv_in,
    const float* __restrict__ env, const float* __restrict__ night,
    const float* __restrict__ wzT, const float* __restrict__ whT,
    const float* __restrict__ linW, const float* __restrict__ linb,
    __half* __restrict__ Xh,
    const __half* __restrict__ TxoH, const __half* __restrict__ TxiH,
    float* __restrict__ out, int t)
{
    __shared__ float f_s[32][36];
    __shared__ float part_s[2][32];
    int tid = threadIdx.x;
    int base = blockIdx.x * 32;

    // ---- phase A: T2 for this block's 32 nodes, straight into LDS ----
    {
        int nl = tid >> 3;
        int dir = (tid >> 2) & 1, sub = tid & 3;
        int node = base + nl;
        int nc = node < Nn ? node : Nn - 1;   // clamp; output stores guarded
        const int*      st  = dir ? startC : startR;
        const int*      to  = dir ? totC : totR;
        const unsigned* adj = dir ? adjC : adjR;
        const __half*   src = dir ? TxiH : TxoH;
        int b = st[nc], e = b + to[nc];
        float a[7] = {0.f, 0.f, 0.f, 0.f, 0.f, 0.f, 0.f};
        int k = b + sub;
        for (; k + 12 < e; k += 16) {
            unsigned e0 = adj[k], e1 = adj[k + 4], e2 = adj[k + 8], e3 = adj[k + 12];
            uint4 r0 = *(const uint4*)(src + (long)(e0 >> 16) * 8);
            uint4 r1 = *(const uint4*)(src + (long)(e1 >> 16) * 8);
            uint4 r2 = *(const uint4*)(src + (long)(e2 >> 16) * 8);
            uint4 r3 = *(const uint4*)(src + (long)(e3 >> 16) * 8);
            float w0 = wdec(e0), w1 = wdec(e1), w2 = wdec(e2), w3 = wdec(e3);
            acc7(a, w0, r0); acc7(a, w1, r1); acc7(a, w2, r2); acc7(a, w3, r3);
        }
        for (; k < e; k += 4) {
            unsigned ed = adj[k];
            uint4 rv = *(const uint4*)(src + (long)(ed >> 16) * 8);
            acc7(a, wdec(ed), rv);
        }
        #pragma unroll
        for (int m = 1; m <= 2; m <<= 1) {
            #pragma unroll
            for (int q = 0; q < 7; q++) a[q] += __shfl_xor(a[q], m);
        }
        if (sub == 0) {
            float s2 = 2.f * (dir ? inv_in[nc] : inv_out[nc]);
            float xv[7], tx[7];
            unpack8(Xh + (long)nc * 8, xv);
            unpack8(src + (long)nc * 8, tx);
            #pragma unroll
            for (int q = 0; q < 7; q++) {
                f_s[nl][21 + 7 * dir + q] = fmaf(s2, a[q], -xv[q]);
                f_s[nl][7 + 7 * dir + q]  = tx[q];
            }
            if (dir == 0) {
                #pragma unroll
                for (int q = 0; q < 7; q++) f_s[nl][q] = xv[q];
                f_s[nl][35] = 1.f;
            }
        }
    }
    __syncthreads();

    // ---- phase B: dense 36x128x2 contraction + activations + output ----
    int lane = tid & 63;
    int wave = tid >> 6;
    int chSel = wave & 1;
    int ch = chSel * 64 + lane;
    int half_id = wave >> 1;
    float wz[36], wh[36];
    #pragma unroll
    for (int k = 0; k < 36; k++) wz[k] = wzT[k * 128 + ch];
    #pragma unroll
    for (int k = 0; k < 36; k++) wh[k] = whT[k * 128 + ch];
    float lw = linW[ch];
    float lb = linb[0];

    #pragma unroll 1
    for (int n = 0; n < 16; n++) {
        int ni = half_id * 16 + n;
        const float4* fv = (const float4*)f_s[ni];
        float hz = 0.f, hh = 0.f;
        #pragma unroll
        for (int q = 0; q < 9; q++) {
            float4 fq = fv[q];
            hz = fmaf(fq.x, wz[q*4+0], hz); hh = fmaf(fq.x, wh[q*4+0], hh);
            hz = fmaf(fq.y, wz[q*4+1], hz); hh = fmaf(fq.y, wh[q*4+1], hh);
            hz = fmaf(fq.z, wz[q*4+2], hz); hh = fmaf(fq.z, wh[q*4+2], hh);
            hz = fmaf(fq.w, wz[q*4+3], hz); hh = fmaf(fq.w, wh[q*4+3], hh);
        }
        float z  = 1.f / (1.f + __expf(-hz));
        float e2 = __expf(2.f * hh);
        float ht = 1.f - 2.f / (e2 + 1.f);
        float v = fmaxf((1.f - z) * ht, 0.f) * lw;
        v += __shfl_xor(v, 1);  v += __shfl_xor(v, 2);  v += __shfl_xor(v, 4);
        v += __shfl_xor(v, 8);  v += __shfl_xor(v, 16); v += __shfl_xor(v, 32);
        if (lane == 0) part_s[chSel][ni] = v;
    }
    __syncthreads();
    if (tid < 32) {
        int node = base + tid;
        if (node < Nn) {
            float o = part_s[0][tid] + part_s[1][tid] + lb;
            o *= night[(long)node * 13 + t + 1];
            out[(long)node * 13 + t + 1] = o;
            if (t + 1 < Tt) {
                __half* xr = Xh + (long)node * 8;
                xr[0] = __float2half(o);
                #pragma unroll
                for (int c = 0; c < 4; c++)
                    xr[1 + c] = __float2half(env[(long)node * 48 + c * 12 + t + 1]);
            }
        }
    }
}

extern "C" void kernel_launch(void* const* d_in, const int* in_sizes, int n_in,
                              void* d_out, int out_size, void* d_ws, size_t ws_size,
                              hipStream_t stream) {
    const float* x      = (const float*)d_in[0];
    const float* env    = (const float*)d_in[1];
    const float* coords = (const float*)d_in[2];
    const int*   ei     = (const int*)d_in[3];
    const float* ew     = (const float*)d_in[4];
    const float* night  = (const float*)d_in[5];
    const float* Wz     = (const float*)d_in[6];
    const float* bz     = (const float*)d_in[7];
    // d_in[8]=Wr, d_in[9]=br unused (R gate never affects output)
    const float* Wh     = (const float*)d_in[10];
    const float* bh     = (const float*)d_in[11];
    const float* linW   = (const float*)d_in[12];
    const float* linb   = (const float*)d_in[13];
    float* out = (float*)d_out;

    float* w = (float*)d_ws;
    float* wzT     = w;                     // 36*128
    float* whT     = w + 4608;
    float* inv_out = w + 9216;              // N
    float* inv_in  = w + 59216;
    __half* Xh   = (__half*)(w + 109216);   // N x 8 halves
    __half* TxoH = (__half*)(w + 309216);
    __half* TxiH = (__half*)(w + 509216);
    int* ibase   = (int*)(w + 709216);
    int* tot     = ibase;                   // 2 x N   (totR | totC)
    int* start   = ibase + 100000;          // 2 x N
    int* cntCh   = ibase + 200000;          // 2 x 16 x N
    int* bsum    = ibase + 1800000;         // 2 x 256
    int* bbase   = ibase + 1800512;
    unsigned* adjR = (unsigned*)(ibase + 1801024);   // E x 4B
    unsigned* adjC = adjR + Ee;

    // ---- atomic-free CSR build (no memset needed) ----
    pass1_kernel<<<NCH * NBAND, 256, 0, stream>>>(ei, cntCh);
    scanA_kernel<<<dim3(SCB, 2), 256, 0, stream>>>(cntCh, tot, bsum);
    scanB_kernel<<<2, 256, 0, stream>>>(bsum, bbase);
    scanC_kernel<<<dim3(SCB, 2), 256, 0, stream>>>(tot, bbase, start);
    pass2_kernel<<<NCH * NBAND, 256, 0, stream>>>(ei, ew, cntCh, start, adjR, adjC);

    weff_kernel<<<(2 * 36 * 128 + 255) / 256, 256, 0, stream>>>(Wz, Wh, bz, bh, wzT, whT);
    init_kernel<<<(Nn + 255) / 256, 256, 0, stream>>>(x, env, coords, Xh, out);

    const int* startR = start;
    const int* startC = start + Nn;
    const int* totR   = tot;
    const int* totC   = tot + Nn;
    for (int t = 0; t < Tt; t++) {
        gather1_kernel<<<(Nn * 8 + 255) / 256, 256, 0, stream>>>(
            startR, totR, adjR, startC, totC, adjC, Xh, TxoH, TxiH, inv_out, inv_in);
        step2_kernel<<<(Nn + 31) / 32, 256, 0, stream>>>(
            startR, totR, adjR, startC, totC, adjC, inv_out, inv_in,
            env, night, wzT, whT, linW, linb, Xh, TxoH, TxiH, out, t);
    }
}

// Round 11
// 830.760 us; speedup vs baseline: 3.5694x; 1.2052x over previous
//
#include <hip/hip_runtime.h>
#include <hip/hip_fp16.h>

#define Nn 50000
#define Ee 800000
#define Tt 12
#define NBAND 8
#define BAND 6250        // Nn / NBAND
#define NCH 16           // edge chunks for histogram
#define CHSZ 50000       // Ee / NCH
#define SCB 196          // scan blocks per dir: 196*256 >= Nn
// HID=128, K=3, F_IN=7, effective features = 35 (+1 bias slot)
// Node feature rows: 8 x f16 = 16 B (one dwordx4 gather).
// Adjacency entry: (src_node << 16) | half_bits(edge_weight) -- 4 bytes.
// Build: LDS-histogram counts (no device atomics) + proven banded atomic scatter.

// ======== pass1: per-(chunk,band) LDS histogram -> cntCh (both dirs) =======
// [proven under replay harness in rounds 8 and 9]
__global__ __launch_bounds__(256) void pass1_kernel(
    const int* __restrict__ ei, int* __restrict__ cntCh)
{
    __shared__ int hR[BAND], hC[BAND];
    int j = blockIdx.x >> 3;        // chunk
    int b = blockIdx.x & 7;         // band
    int lo = b * BAND;
    for (int i = threadIdx.x; i < BAND; i += 256) { hR[i] = 0; hC[i] = 0; }
    __syncthreads();
    int e0 = j * CHSZ;
    for (int e = e0 + threadIdx.x; e < e0 + CHSZ; e += 256) {
        int r = __builtin_nontemporal_load(ei + e);
        int c = __builtin_nontemporal_load(ei + Ee + e);
        if ((unsigned)(r - lo) < BAND) atomicAdd(&hR[r - lo], 1);
        if ((unsigned)(c - lo) < BAND) atomicAdd(&hC[c - lo], 1);
    }
    __syncthreads();
    for (int i = threadIdx.x; i < BAND; i += 256) {
        cntCh[(0 * NCH + j) * Nn + lo + i] = hR[i];
        cntCh[(1 * NCH + j) * Nn + lo + i] = hC[i];
    }
}

// ---- scanA: node total over chunks (cntCh read-only) + block sums ---------
// [proven rounds 8/9]
__global__ __launch_bounds__(256) void scanA_kernel(
    const int* __restrict__ cntCh, int* __restrict__ tot, int* __restrict__ bsum)
{
    int y = blockIdx.y;
    int i = blockIdx.x * 256 + threadIdx.x;
    int v = 0;
    if (i < Nn) {
        #pragma unroll
        for (int j = 0; j < NCH; j++) v += cntCh[(y * NCH + j) * Nn + i];
        tot[y * Nn + i] = v;
    }
    __shared__ int ws_[4];
    int s = v;
    s += __shfl_xor(s, 1);  s += __shfl_xor(s, 2);  s += __shfl_xor(s, 4);
    s += __shfl_xor(s, 8);  s += __shfl_xor(s, 16); s += __shfl_xor(s, 32);
    if ((threadIdx.x & 63) == 0) ws_[threadIdx.x >> 6] = s;
    __syncthreads();
    if (threadIdx.x == 0)
        bsum[y * 256 + blockIdx.x] = ws_[0] + ws_[1] + ws_[2] + ws_[3];
}

__global__ __launch_bounds__(256) void scanB_kernel(
    const int* __restrict__ bsum, int* __restrict__ bbase)
{
    int y = blockIdx.x;
    __shared__ int s[256];
    int t = threadIdx.x;
    int v = (t < SCB) ? bsum[y * 256 + t] : 0;
    s[t] = v;
    __syncthreads();
    for (int off = 1; off < 256; off <<= 1) {
        int u = (t >= off) ? s[t - off] : 0;
        __syncthreads();
        s[t] += u;
        __syncthreads();
    }
    bbase[y * 256 + t] = s[t] - v;   // exclusive
}

// ---- scanC: exclusive node scan -> start AND next (scatter cursors) -------
// [round 5's proven start+next pattern]
__global__ __launch_bounds__(256) void scanC_kernel(
    const int* __restrict__ tot, const int* __restrict__ bbase,
    int* __restrict__ start, int* __restrict__ nxt)
{
    int y = blockIdx.y;
    int i = blockIdx.x * 256 + threadIdx.x;
    int v = (i < Nn) ? tot[y * Nn + i] : 0;
    __shared__ int s[256];
    int t = threadIdx.x;
    s[t] = v;
    __syncthreads();
    for (int off = 1; off < 256; off <<= 1) {
        int u = (t >= off) ? s[t - off] : 0;
        __syncthreads();
        s[t] += u;
        __syncthreads();
    }
    if (i < Nn) {
        int st = bbase[y * 256 + blockIdx.x] + s[t] - v;
        start[y * Nn + i] = st;
        nxt[y * Nn + i] = st;
    }
}

// ---- banded device-atomic scatter [proven rounds 5/6/7] -------------------
__global__ __launch_bounds__(256) void scatter_banded(
    const int* __restrict__ ei, const float* __restrict__ ew,
    int* __restrict__ nextR, int* __restrict__ nextC,
    unsigned* __restrict__ adjR, unsigned* __restrict__ adjC)
{
    int band = blockIdx.x & (NBAND - 1);
    int chunk = blockIdx.x >> 3;
    int lo = band * BAND, hi = lo + BAND;
    int stride = (gridDim.x >> 3) * 256;
    for (int e = chunk * 256 + threadIdx.x; e < Ee; e += stride) {
        int r = ei[e], c = ei[Ee + e];
        bool wr = (r >= lo && r < hi);
        bool wc = (c >= lo && c < hi);
        if (!(wr || wc)) continue;
        unsigned wb = __half_as_ushort(__float2half(ew[e]));
        if (wr) adjR[atomicAdd(&nextR[r], 1)] = ((unsigned)c << 16) | wb;
        if (wc) adjC[atomicAdd(&nextC[c], 1)] = ((unsigned)r << 16) | wb;
    }
}

// ==== effective weights, layout [gate][k*128 + j], k=35 is the bias row ====
// f layout: [0..6]=X, [7..13]=Tx_o, [14..20]=Tx_i, [21..27]=T2_o, [28..34]=T2_i, [35]=1
__global__ __launch_bounds__(256) void weff_kernel(
    const float* __restrict__ Wz, const float* __restrict__ Wh,
    const float* __restrict__ bz, const float* __restrict__ bh,
    float* __restrict__ wzT, float* __restrict__ whT)
{
    int idx = blockIdx.x * 256 + threadIdx.x;
    if (idx >= 2 * 36 * 128) return;
    const float* W = (idx < 36 * 128) ? Wz : Wh;
    const float* B = (idx < 36 * 128) ? bz : bh;
    float* O       = (idx < 36 * 128) ? wzT : whT;
    int rem = idx % (36 * 128);
    int k = rem / 128, j = rem % 128;
    float v;
    if (k == 35) v = B[j];
    else {
        int p = k / 7, rr = k % 7;
        if (p == 0)      v = W[(0 * 135 + rr) * 128 + j] + W[(3 * 135 + rr) * 128 + j];
        else if (p == 1) v = W[(1 * 135 + rr) * 128 + j];
        else if (p == 2) v = W[(4 * 135 + rr) * 128 + j];
        else if (p == 3) v = W[(2 * 135 + rr) * 128 + j];
        else             v = W[(5 * 135 + rr) * 128 + j];
    }
    O[k * 128 + j] = v;
}

// =================== init: Xh row (f16) and out column 0 ===================
__global__ __launch_bounds__(256) void init_kernel(
    const float* __restrict__ x, const float* __restrict__ env,
    const float* __restrict__ coords, __half* __restrict__ Xh,
    float* __restrict__ out)
{
    int i = blockIdx.x * 256 + threadIdx.x;
    if (i >= Nn) return;
    float xv = x[i * Tt];
    __half* r = Xh + (long)i * 8;
    r[0] = __float2half(xv);
    #pragma unroll
    for (int c = 0; c < 4; c++) r[1 + c] = __float2half(env[i * 48 + c * 12]);
    r[5] = __float2half(coords[i * 2 + 0]);
    r[6] = __float2half(coords[i * 2 + 1]);
    r[7] = __half(0.f);
    out[i * 13 + 0] = xv;
}

__device__ __forceinline__ void unpack8(const __half* p, float* v) {
    uint4 hv = *((const uint4*)p);
    float2 p0 = __half22float2(*(__half2*)&hv.x);
    float2 p1 = __half22float2(*(__half2*)&hv.y);
    float2 p2 = __half22float2(*(__half2*)&hv.z);
    float2 p3 = __half22float2(*(__half2*)&hv.w);
    v[0] = p0.x; v[1] = p0.y; v[2] = p1.x; v[3] = p1.y;
    v[4] = p2.x; v[5] = p2.y; v[6] = p3.x;
}

__device__ __forceinline__ void pack8(__half* p, const float* v) {
    __half2 q0 = __floats2half2_rn(v[0], v[1]);
    __half2 q1 = __floats2half2_rn(v[2], v[3]);
    __half2 q2 = __floats2half2_rn(v[4], v[5]);
    __half2 q3 = __floats2half2_rn(v[6], 0.f);
    uint4 st;
    st.x = *(unsigned*)&q0; st.y = *(unsigned*)&q1;
    st.z = *(unsigned*)&q2; st.w = *(unsigned*)&q3;
    *((uint4*)p) = st;
}

__device__ __forceinline__ void acc7(float* a, float w, uint4 hv) {
    float2 p0 = __half22float2(*(__half2*)&hv.x);
    float2 p1 = __half22float2(*(__half2*)&hv.y);
    float2 p2 = __half22float2(*(__half2*)&hv.z);
    float2 p3 = __half22float2(*(__half2*)&hv.w);
    a[0] = fmaf(w, p0.x, a[0]); a[1] = fmaf(w, p0.y, a[1]);
    a[2] = fmaf(w, p1.x, a[2]); a[3] = fmaf(w, p1.y, a[3]);
    a[4] = fmaf(w, p2.x, a[4]); a[5] = fmaf(w, p2.y, a[5]);
    a[6] = fmaf(w, p3.x, a[6]);
}

__device__ __forceinline__ float wdec(unsigned ed) {
    return __half2float(__ushort_as_half((unsigned short)(ed & 0xffffu)));
}

// ============== gather pass 1: Tx = inv * segsum(w * Xh[src]) ==============
// [round 7 verbatim] 8 threads per node: bit2 = dir, bits0-1 = sub; x4 MLP.
__global__ __launch_bounds__(256) void gather1_kernel(
    const int* __restrict__ startR, const int* __restrict__ totR,
    const unsigned* __restrict__ adjR,
    const int* __restrict__ startC, const int* __restrict__ totC,
    const unsigned* __restrict__ adjC,
    const __half* __restrict__ Xh,
    __half* __restrict__ TxoH, __half* __restrict__ TxiH,
    float* __restrict__ inv_out, float* __restrict__ inv_in)
{
    int tid = blockIdx.x * 256 + threadIdx.x;
    if (tid >= Nn * 8) return;
    int node = tid >> 3;
    int dir = (tid >> 2) & 1, sub = tid & 3;
    const int*      st  = dir ? startC : startR;
    const int*      to  = dir ? totC : totR;
    const unsigned* adj = dir ? adjC : adjR;
    int b = st[node], e = b + to[node];
    float a[7] = {0.f, 0.f, 0.f, 0.f, 0.f, 0.f, 0.f};
    float sw = 0.f;
    int k = b + sub;
    for (; k + 12 < e; k += 16) {
        unsigned e0 = adj[k], e1 = adj[k + 4], e2 = adj[k + 8], e3 = adj[k + 12];
        uint4 r0 = *(const uint4*)(Xh + (long)(e0 >> 16) * 8);
        uint4 r1 = *(const uint4*)(Xh + (long)(e1 >> 16) * 8);
        uint4 r2 = *(const uint4*)(Xh + (long)(e2 >> 16) * 8);
        uint4 r3 = *(const uint4*)(Xh + (long)(e3 >> 16) * 8);
        float w0 = wdec(e0), w1 = wdec(e1), w2 = wdec(e2), w3 = wdec(e3);
        acc7(a, w0, r0); acc7(a, w1, r1); acc7(a, w2, r2); acc7(a, w3, r3);
        sw += (w0 + w1) + (w2 + w3);
    }
    for (; k < e; k += 4) {
        unsigned ed = adj[k];
        uint4 rv = *(const uint4*)(Xh + (long)(ed >> 16) * 8);
        float w = wdec(ed);
        acc7(a, w, rv);
        sw += w;
    }
    #pragma unroll
    for (int m = 1; m <= 2; m <<= 1) {
        #pragma unroll
        for (int q = 0; q < 7; q++) a[q] += __shfl_xor(a[q], m);
        sw += __shfl_xor(sw, m);
    }
    if (sub == 0) {
        float inv = sw > 0.f ? 1.f / sw : 0.f;
        (dir ? inv_in : inv_out)[node] = inv;
        #pragma unroll
        for (int q = 0; q < 7; q++) a[q] *= inv;
        pack8((dir ? TxiH : TxoH) + (long)node * 8, a);
    }
}

// ====== fused step2 [round 7 verbatim]: T2 gather (LDS, fp32) + dense ======
__global__ __launch_bounds__(256) void step2_kernel(
    const int* __restrict__ startR, const int* __restrict__ totR,
    const unsigned* __restrict__ adjR,
    const int* __restrict__ startC, const int* __restrict__ totC,
    const unsigned* __restrict__ adjC,
    const float* __restrict__ inv_out, const float* __restrict__ inv_in,
    const float* __restrict__ env, const float* __restrict__ night,
    const float* __restrict__ wzT, const float* __restrict__ whT,
    const float* __restrict__ linW, const float* __restrict__ linb,
    __half* __restrict__ Xh,
    const __half* __restrict__ TxoH, const __half* __restrict__ TxiH,
    float* __restrict__ out, int t)
{
    __shared__ float f_s[32][36];
    __shared__ float part_s[2][32];
    int tid = threadIdx.x;
    int base = blockIdx.x * 32;

    {
        int nl = tid >> 3;
        int dir = (tid >> 2) & 1, sub = tid & 3;
        int node = base + nl;
        int nc = node < Nn ? node : Nn - 1;   // clamp; output stores guarded
        const int*      st  = dir ? startC : startR;
        const int*      to  = dir ? totC : totR;
        const unsigned* adj = dir ? adjC : adjR;
        const __half*   src = dir ? TxiH : TxoH;
        int b = st[nc], e = b + to[nc];
        float a[7] = {0.f, 0.f, 0.f, 0.f, 0.f, 0.f, 0.f};
        int k = b + sub;
        for (; k + 12 < e; k += 16) {
            unsigned e0 = adj[k], e1 = adj[k + 4], e2 = adj[k + 8], e3 = adj[k + 12];
            uint4 r0 = *(const uint4*)(src + (long)(e0 >> 16) * 8);
            uint4 r1 = *(const uint4*)(src + (long)(e1 >> 16) * 8);
            uint4 r2 = *(const uint4*)(src + (long)(e2 >> 16) * 8);
            uint4 r3 = *(const uint4*)(src + (long)(e3 >> 16) * 8);
            float w0 = wdec(e0), w1 = wdec(e1), w2 = wdec(e2), w3 = wdec(e3);
            acc7(a, w0, r0); acc7(a, w1, r1); acc7(a, w2, r2); acc7(a, w3, r3);
        }
        for (; k < e; k += 4) {
            unsigned ed = adj[k];
            uint4 rv = *(const uint4*)(src + (long)(ed >> 16) * 8);
            acc7(a, wdec(ed), rv);
        }
        #pragma unroll
        for (int m = 1; m <= 2; m <<= 1) {
            #pragma unroll
            for (int q = 0; q < 7; q++) a[q] += __shfl_xor(a[q], m);
        }
        if (sub == 0) {
            float s2 = 2.f * (dir ? inv_in[nc] : inv_out[nc]);
            float xv[7], tx[7];
            unpack8(Xh + (long)nc * 8, xv);
            unpack8(src + (long)nc * 8, tx);
            #pragma unroll
            for (int q = 0; q < 7; q++) {
                f_s[nl][21 + 7 * dir + q] = fmaf(s2, a[q], -xv[q]);
                f_s[nl][7 + 7 * dir + q]  = tx[q];
            }
            if (dir == 0) {
                #pragma unroll
                for (int q = 0; q < 7; q++) f_s[nl][q] = xv[q];
                f_s[nl][35] = 1.f;
            }
        }
    }
    __syncthreads();

    int lane = tid & 63;
    int wave = tid >> 6;
    int chSel = wave & 1;
    int ch = chSel * 64 + lane;
    int half_id = wave >> 1;
    float wz[36], wh[36];
    #pragma unroll
    for (int k = 0; k < 36; k++) wz[k] = wzT[k * 128 + ch];
    #pragma unroll
    for (int k = 0; k < 36; k++) wh[k] = whT[k * 128 + ch];
    float lw = linW[ch];
    float lb = linb[0];

    #pragma unroll 1
    for (int n = 0; n < 16; n++) {
        int ni = half_id * 16 + n;
        const float4* fv = (const float4*)f_s[ni];
        float hz = 0.f, hh = 0.f;
        #pragma unroll
        for (int q = 0; q < 9; q++) {
            float4 fq = fv[q];
            hz = fmaf(fq.x, wz[q*4+0], hz); hh = fmaf(fq.x, wh[q*4+0], hh);
            hz = fmaf(fq.y, wz[q*4+1], hz); hh = fmaf(fq.y, wh[q*4+1], hh);
            hz = fmaf(fq.z, wz[q*4+2], hz); hh = fmaf(fq.z, wh[q*4+2], hh);
            hz = fmaf(fq.w, wz[q*4+3], hz); hh = fmaf(fq.w, wh[q*4+3], hh);
        }
        float z  = 1.f / (1.f + __expf(-hz));
        float e2 = __expf(2.f * hh);
        float ht = 1.f - 2.f / (e2 + 1.f);
        float v = fmaxf((1.f - z) * ht, 0.f) * lw;
        v += __shfl_xor(v, 1);  v += __shfl_xor(v, 2);  v += __shfl_xor(v, 4);
        v += __shfl_xor(v, 8);  v += __shfl_xor(v, 16); v += __shfl_xor(v, 32);
        if (lane == 0) part_s[chSel][ni] = v;
    }
    __syncthreads();
    if (tid < 32) {
        int node = base + tid;
        if (node < Nn) {
            float o = part_s[0][tid] + part_s[1][tid] + lb;
            o *= night[(long)node * 13 + t + 1];
            out[(long)node * 13 + t + 1] = o;
            if (t + 1 < Tt) {
                __half* xr = Xh + (long)node * 8;
                xr[0] = __float2half(o);
                #pragma unroll
                for (int c = 0; c < 4; c++)
                    xr[1 + c] = __float2half(env[(long)node * 48 + c * 12 + t + 1]);
            }
        }
    }
}

extern "C" void kernel_launch(void* const* d_in, const int* in_sizes, int n_in,
                              void* d_out, int out_size, void* d_ws, size_t ws_size,
                              hipStream_t stream) {
    const float* x      = (const float*)d_in[0];
    const float* env    = (const float*)d_in[1];
    const float* coords = (const float*)d_in[2];
    const int*   ei     = (const int*)d_in[3];
    const float* ew     = (const float*)d_in[4];
    const float* night  = (const float*)d_in[5];
    const float* Wz     = (const float*)d_in[6];
    const float* bz     = (const float*)d_in[7];
    // d_in[8]=Wr, d_in[9]=br unused (R gate never affects output)
    const float* Wh     = (const float*)d_in[10];
    const float* bh     = (const float*)d_in[11];
    const float* linW   = (const float*)d_in[12];
    const float* linb   = (const float*)d_in[13];
    float* out = (float*)d_out;

    float* w = (float*)d_ws;
    float* wzT     = w;                     // 36*128
    float* whT     = w + 4608;
    float* inv_out = w + 9216;              // N
    float* inv_in  = w + 59216;
    __half* Xh   = (__half*)(w + 109216);   // N x 8 halves
    __half* TxoH = (__half*)(w + 309216);
    __half* TxiH = (__half*)(w + 509216);
    int* ibase   = (int*)(w + 709216);
    int* tot     = ibase;                   // 2 x N
    int* start   = ibase + 100000;          // 2 x N
    int* next    = ibase + 200000;          // 2 x N
    int* cntCh   = ibase + 300000;          // 2 x 16 x N
    int* bsum    = ibase + 1900000;         // 2 x 256
    int* bbase   = bsum + 512;
    unsigned* adjR = (unsigned*)(ibase + 1901024);   // E x 4B
    unsigned* adjC = adjR + Ee;             // ends at ibase + 3501024 (16.84 MB total)

    // ---- build: LDS-hist counts + scans + proven banded atomic scatter ----
    pass1_kernel<<<NCH * NBAND, 256, 0, stream>>>(ei, cntCh);
    scanA_kernel<<<dim3(SCB, 2), 256, 0, stream>>>(cntCh, tot, bsum);
    scanB_kernel<<<2, 256, 0, stream>>>(bsum, bbase);
    scanC_kernel<<<dim3(SCB, 2), 256, 0, stream>>>(tot, bbase, start, next);
    scatter_banded<<<8 * 256, 256, 0, stream>>>(ei, ew, next, next + Nn, adjR, adjC);

    weff_kernel<<<(2 * 36 * 128 + 255) / 256, 256, 0, stream>>>(Wz, Wh, bz, bh, wzT, whT);
    init_kernel<<<(Nn + 255) / 256, 256, 0, stream>>>(x, env, coords, Xh, out);

    const int* startR = start;
    const int* startC = start + Nn;
    const int* totR   = tot;
    const int* totC   = tot + Nn;
    for (int t = 0; t < Tt; t++) {
        gather1_kernel<<<(Nn * 8 + 255) / 256, 256, 0, stream>>>(
            startR, totR, adjR, startC, totC, adjC, Xh, TxoH, TxiH, inv_out, inv_in);
        step2_kernel<<<(Nn + 31) / 32, 256, 0, stream>>>(
            startR, totR, adjR, startC, totC, adjC, inv_out, inv_in,
            env, night, wzT, whT, linW, linb, Xh, TxoH, TxiH, out, t);
    }
}

// Round 12
// 788.469 us; speedup vs baseline: 3.7608x; 1.0536x over previous
//
#include <hip/hip_runtime.h>
#include <hip/hip_fp16.h>

#define Nn 50000
#define Ee 800000
#define Tt 12
#define NBAND 8
#define BAND 6250        // Nn / NBAND exactly
#define SCB 196          // scan blocks per dir: 196*256 >= Nn
// HID=128, K=3, F_IN=7, effective features = 35 (+1 bias slot)
// Node feature rows: 8 x f16 = 16 B (one dwordx4 gather).
// Adjacency entry: (src_node << 16) | half_bits(edge_weight) -- 4 bytes.
// Build = round 5's proven kernels; loop = round 7's proven kernels.

// =================== degree histogram [proven r2-r5] =======================
__global__ __launch_bounds__(256) void hist_kernel(
    const int* __restrict__ ei, int* __restrict__ cntR, int* __restrict__ cntC)
{
    int e = blockIdx.x * 256 + threadIdx.x;
    if (e >= Ee) return;
    atomicAdd(&cntR[ei[e]], 1);
    atomicAdd(&cntC[ei[Ee + e]], 1);
}

// ---- 3-phase multi-block exclusive scan of cntR / cntC [proven r5-r7] -----
__global__ __launch_bounds__(256) void scanA_kernel(
    const int* __restrict__ cntR, const int* __restrict__ cntC,
    int* __restrict__ bsum)
{
    const int* cnt = blockIdx.y ? cntC : cntR;
    int i = blockIdx.x * 256 + threadIdx.x;
    int v = (i < Nn) ? cnt[i] : 0;
    __shared__ int ws_[4];
    v += __shfl_xor(v, 1);  v += __shfl_xor(v, 2);  v += __shfl_xor(v, 4);
    v += __shfl_xor(v, 8);  v += __shfl_xor(v, 16); v += __shfl_xor(v, 32);
    if ((threadIdx.x & 63) == 0) ws_[threadIdx.x >> 6] = v;
    __syncthreads();
    if (threadIdx.x == 0)
        bsum[blockIdx.y * 256 + blockIdx.x] = ws_[0] + ws_[1] + ws_[2] + ws_[3];
}

__global__ __launch_bounds__(256) void scanB_kernel(
    const int* __restrict__ bsum, int* __restrict__ bbase)
{
    int y = blockIdx.x;
    __shared__ int s[256];
    int t = threadIdx.x;
    int v = (t < SCB) ? bsum[y * 256 + t] : 0;
    s[t] = v;
    __syncthreads();
    for (int off = 1; off < 256; off <<= 1) {
        int u = (t >= off) ? s[t - off] : 0;
        __syncthreads();
        s[t] += u;
        __syncthreads();
    }
    bbase[y * 256 + t] = s[t] - v;   // exclusive
}

__global__ __launch_bounds__(256) void scanC_kernel(
    const int* __restrict__ cntR, const int* __restrict__ cntC,
    const int* __restrict__ bbase,
    int* __restrict__ startR, int* __restrict__ startC,
    int* __restrict__ nextR, int* __restrict__ nextC)
{
    int y = blockIdx.y;
    const int* cnt = y ? cntC : cntR;
    int* start     = y ? startC : startR;
    int* nxt       = y ? nextC : nextR;
    int i = blockIdx.x * 256 + threadIdx.x;
    int v = (i < Nn) ? cnt[i] : 0;
    __shared__ int s[256];
    int t = threadIdx.x;
    s[t] = v;
    __syncthreads();
    for (int off = 1; off < 256; off <<= 1) {
        int u = (t >= off) ? s[t - off] : 0;
        __syncthreads();
        s[t] += u;
        __syncthreads();
    }
    int st = bbase[y * 256 + blockIdx.x] + s[t] - v;
    if (i < Nn) { start[i] = st; nxt[i] = st; }
}

// ---- banded device-atomic scatter [proven r5/r11] -------------------------
__global__ __launch_bounds__(256) void scatter_banded(
    const int* __restrict__ ei, const float* __restrict__ ew,
    int* __restrict__ nextR, int* __restrict__ nextC,
    unsigned* __restrict__ adjR, unsigned* __restrict__ adjC)
{
    int band = blockIdx.x & (NBAND - 1);
    int chunk = blockIdx.x >> 3;
    int lo = band * BAND, hi = lo + BAND;
    int stride = (gridDim.x >> 3) * 256;
    for (int e = chunk * 256 + threadIdx.x; e < Ee; e += stride) {
        int r = ei[e], c = ei[Ee + e];
        bool wr = (r >= lo && r < hi);
        bool wc = (c >= lo && c < hi);
        if (!(wr || wc)) continue;
        unsigned wb = __half_as_ushort(__float2half(ew[e]));
        if (wr) adjR[atomicAdd(&nextR[r], 1)] = ((unsigned)c << 16) | wb;
        if (wc) adjC[atomicAdd(&nextC[c], 1)] = ((unsigned)r << 16) | wb;
    }
}

// ==== effective weights, layout [gate][k*128 + j], k=35 is the bias row ====
// f layout: [0..6]=X, [7..13]=Tx_o, [14..20]=Tx_i, [21..27]=T2_o, [28..34]=T2_i, [35]=1
__global__ __launch_bounds__(256) void weff_kernel(
    const float* __restrict__ Wz, const float* __restrict__ Wh,
    const float* __restrict__ bz, const float* __restrict__ bh,
    float* __restrict__ wzT, float* __restrict__ whT)
{
    int idx = blockIdx.x * 256 + threadIdx.x;
    if (idx >= 2 * 36 * 128) return;
    const float* W = (idx < 36 * 128) ? Wz : Wh;
    const float* B = (idx < 36 * 128) ? bz : bh;
    float* O       = (idx < 36 * 128) ? wzT : whT;
    int rem = idx % (36 * 128);
    int k = rem / 128, j = rem % 128;
    float v;
    if (k == 35) v = B[j];
    else {
        int p = k / 7, rr = k % 7;
        if (p == 0)      v = W[(0 * 135 + rr) * 128 + j] + W[(3 * 135 + rr) * 128 + j];
        else if (p == 1) v = W[(1 * 135 + rr) * 128 + j];
        else if (p == 2) v = W[(4 * 135 + rr) * 128 + j];
        else if (p == 3) v = W[(2 * 135 + rr) * 128 + j];
        else             v = W[(5 * 135 + rr) * 128 + j];
    }
    O[k * 128 + j] = v;
}

// =================== init: Xh row (f16) and out column 0 ===================
__global__ __launch_bounds__(256) void init_kernel(
    const float* __restrict__ x, const float* __restrict__ env,
    const float* __restrict__ coords, __half* __restrict__ Xh,
    float* __restrict__ out)
{
    int i = blockIdx.x * 256 + threadIdx.x;
    if (i >= Nn) return;
    float xv = x[i * Tt];
    __half* r = Xh + (long)i * 8;
    r[0] = __float2half(xv);
    #pragma unroll
    for (int c = 0; c < 4; c++) r[1 + c] = __float2half(env[i * 48 + c * 12]);
    r[5] = __float2half(coords[i * 2 + 0]);
    r[6] = __float2half(coords[i * 2 + 1]);
    r[7] = __half(0.f);
    out[i * 13 + 0] = xv;
}

__device__ __forceinline__ void unpack8(const __half* p, float* v) {
    uint4 hv = *((const uint4*)p);
    float2 p0 = __half22float2(*(__half2*)&hv.x);
    float2 p1 = __half22float2(*(__half2*)&hv.y);
    float2 p2 = __half22float2(*(__half2*)&hv.z);
    float2 p3 = __half22float2(*(__half2*)&hv.w);
    v[0] = p0.x; v[1] = p0.y; v[2] = p1.x; v[3] = p1.y;
    v[4] = p2.x; v[5] = p2.y; v[6] = p3.x;
}

__device__ __forceinline__ void pack8(__half* p, const float* v) {
    __half2 q0 = __floats2half2_rn(v[0], v[1]);
    __half2 q1 = __floats2half2_rn(v[2], v[3]);
    __half2 q2 = __floats2half2_rn(v[4], v[5]);
    __half2 q3 = __floats2half2_rn(v[6], 0.f);
    uint4 st;
    st.x = *(unsigned*)&q0; st.y = *(unsigned*)&q1;
    st.z = *(unsigned*)&q2; st.w = *(unsigned*)&q3;
    *((uint4*)p) = st;
}

__device__ __forceinline__ void acc7(float* a, float w, uint4 hv) {
    float2 p0 = __half22float2(*(__half2*)&hv.x);
    float2 p1 = __half22float2(*(__half2*)&hv.y);
    float2 p2 = __half22float2(*(__half2*)&hv.z);
    float2 p3 = __half22float2(*(__half2*)&hv.w);
    a[0] = fmaf(w, p0.x, a[0]); a[1] = fmaf(w, p0.y, a[1]);
    a[2] = fmaf(w, p1.x, a[2]); a[3] = fmaf(w, p1.y, a[3]);
    a[4] = fmaf(w, p2.x, a[4]); a[5] = fmaf(w, p2.y, a[5]);
    a[6] = fmaf(w, p3.x, a[6]);
}

__device__ __forceinline__ float wdec(unsigned ed) {
    return __half2float(__ushort_as_half((unsigned short)(ed & 0xffffu)));
}

// ============== gather pass 1 [round 7 verbatim] ===========================
// 8 threads per node: bit2 = dir, bits0-1 = sub; x4 MLP batching.
__global__ __launch_bounds__(256) void gather1_kernel(
    const int* __restrict__ startR, const int* __restrict__ cntR,
    const unsigned* __restrict__ adjR,
    const int* __restrict__ startC, const int* __restrict__ cntC,
    const unsigned* __restrict__ adjC,
    const __half* __restrict__ Xh,
    __half* __restrict__ TxoH, __half* __restrict__ TxiH,
    float* __restrict__ inv_out, float* __restrict__ inv_in)
{
    int tid = blockIdx.x * 256 + threadIdx.x;
    if (tid >= Nn * 8) return;
    int node = tid >> 3;
    int dir = (tid >> 2) & 1, sub = tid & 3;
    const int*      st  = dir ? startC : startR;
    const int*      cn  = dir ? cntC : cntR;
    const unsigned* adj = dir ? adjC : adjR;
    int b = st[node], e = b + cn[node];
    float a[7] = {0.f, 0.f, 0.f, 0.f, 0.f, 0.f, 0.f};
    float sw = 0.f;
    int k = b + sub;
    for (; k + 12 < e; k += 16) {
        unsigned e0 = adj[k], e1 = adj[k + 4], e2 = adj[k + 8], e3 = adj[k + 12];
        uint4 r0 = *(const uint4*)(Xh + (long)(e0 >> 16) * 8);
        uint4 r1 = *(const uint4*)(Xh + (long)(e1 >> 16) * 8);
        uint4 r2 = *(const uint4*)(Xh + (long)(e2 >> 16) * 8);
        uint4 r3 = *(const uint4*)(Xh + (long)(e3 >> 16) * 8);
        float w0 = wdec(e0), w1 = wdec(e1), w2 = wdec(e2), w3 = wdec(e3);
        acc7(a, w0, r0); acc7(a, w1, r1); acc7(a, w2, r2); acc7(a, w3, r3);
        sw += (w0 + w1) + (w2 + w3);
    }
    for (; k < e; k += 4) {
        unsigned ed = adj[k];
        uint4 rv = *(const uint4*)(Xh + (long)(ed >> 16) * 8);
        float w = wdec(ed);
        acc7(a, w, rv);
        sw += w;
    }
    #pragma unroll
    for (int m = 1; m <= 2; m <<= 1) {
        #pragma unroll
        for (int q = 0; q < 7; q++) a[q] += __shfl_xor(a[q], m);
        sw += __shfl_xor(sw, m);
    }
    if (sub == 0) {
        float inv = sw > 0.f ? 1.f / sw : 0.f;
        (dir ? inv_in : inv_out)[node] = inv;
        #pragma unroll
        for (int q = 0; q < 7; q++) a[q] *= inv;
        pack8((dir ? TxiH : TxoH) + (long)node * 8, a);
    }
}

// ====== fused step2 [round 7 verbatim]: T2 gather (LDS, fp32) + dense ======
__global__ __launch_bounds__(256) void step2_kernel(
    const int* __restrict__ startR, const int* __restrict__ cntR,
    const unsigned* __restrict__ adjR,
    const int* __restrict__ startC, const int* __restrict__ cntC,
    const unsigned* __restrict__ adjC,
    const float* __restrict__ inv_out, const float* __restrict__ inv_in,
    const float* __restrict__ env, const float* __restrict__ night,
    const float* __restrict__ wzT, const float* __restrict__ whT,
    const float* __restrict__ linW, const float* __restrict__ linb,
    __half* __restrict__ Xh,
    const __half* __restrict__ TxoH, const __half* __restrict__ TxiH,
    float* __restrict__ out, int t)
{
    __shared__ float f_s[32][36];
    __shared__ float part_s[2][32];
    int tid = threadIdx.x;
    int base = blockIdx.x * 32;

    {
        int nl = tid >> 3;
        int dir = (tid >> 2) & 1, sub = tid & 3;
        int node = base + nl;
        int nc = node < Nn ? node : Nn - 1;   // clamp; output stores guarded
        const int*      st  = dir ? startC : startR;
        const int*      cn  = dir ? cntC : cntR;
        const unsigned* adj = dir ? adjC : adjR;
        const __half*   src = dir ? TxiH : TxoH;
        int b = st[nc], e = b + cn[nc];
        float a[7] = {0.f, 0.f, 0.f, 0.f, 0.f, 0.f, 0.f};
        int k = b + sub;
        for (; k + 12 < e; k += 16) {
            unsigned e0 = adj[k], e1 = adj[k + 4], e2 = adj[k + 8], e3 = adj[k + 12];
            uint4 r0 = *(const uint4*)(src + (long)(e0 >> 16) * 8);
            uint4 r1 = *(const uint4*)(src + (long)(e1 >> 16) * 8);
            uint4 r2 = *(const uint4*)(src + (long)(e2 >> 16) * 8);
            uint4 r3 = *(const uint4*)(src + (long)(e3 >> 16) * 8);
            float w0 = wdec(e0), w1 = wdec(e1), w2 = wdec(e2), w3 = wdec(e3);
            acc7(a, w0, r0); acc7(a, w1, r1); acc7(a, w2, r2); acc7(a, w3, r3);
        }
        for (; k < e; k += 4) {
            unsigned ed = adj[k];
            uint4 rv = *(const uint4*)(src + (long)(ed >> 16) * 8);
            acc7(a, wdec(ed), rv);
        }
        #pragma unroll
        for (int m = 1; m <= 2; m <<= 1) {
            #pragma unroll
            for (int q = 0; q < 7; q++) a[q] += __shfl_xor(a[q], m);
        }
        if (sub == 0) {
            float s2 = 2.f * (dir ? inv_in[nc] : inv_out[nc]);
            float xv[7], tx[7];
            unpack8(Xh + (long)nc * 8, xv);
            unpack8(src + (long)nc * 8, tx);
            #pragma unroll
            for (int q = 0; q < 7; q++) {
                f_s[nl][21 + 7 * dir + q] = fmaf(s2, a[q], -xv[q]);
                f_s[nl][7 + 7 * dir + q]  = tx[q];
            }
            if (dir == 0) {
                #pragma unroll
                for (int q = 0; q < 7; q++) f_s[nl][q] = xv[q];
                f_s[nl][35] = 1.f;
            }
        }
    }
    __syncthreads();

    int lane = tid & 63;
    int wave = tid >> 6;
    int chSel = wave & 1;
    int ch = chSel * 64 + lane;
    int half_id = wave >> 1;
    float wz[36], wh[36];
    #pragma unroll
    for (int k = 0; k < 36; k++) wz[k] = wzT[k * 128 + ch];
    #pragma unroll
    for (int k = 0; k < 36; k++) wh[k] = whT[k * 128 + ch];
    float lw = linW[ch];
    float lb = linb[0];

    #pragma unroll 1
    for (int n = 0; n < 16; n++) {
        int ni = half_id * 16 + n;
        const float4* fv = (const float4*)f_s[ni];
        float hz = 0.f, hh = 0.f;
        #pragma unroll
        for (int q = 0; q < 9; q++) {
            float4 fq = fv[q];
            hz = fmaf(fq.x, wz[q*4+0], hz); hh = fmaf(fq.x, wh[q*4+0], hh);
            hz = fmaf(fq.y, wz[q*4+1], hz); hh = fmaf(fq.y, wh[q*4+1], hh);
            hz = fmaf(fq.z, wz[q*4+2], hz); hh = fmaf(fq.z, wh[q*4+2], hh);
            hz = fmaf(fq.w, wz[q*4+3], hz); hh = fmaf(fq.w, wh[q*4+3], hh);
        }
        float z  = 1.f / (1.f + __expf(-hz));
        float e2 = __expf(2.f * hh);
        float ht = 1.f - 2.f / (e2 + 1.f);
        float v = fmaxf((1.f - z) * ht, 0.f) * lw;
        v += __shfl_xor(v, 1);  v += __shfl_xor(v, 2);  v += __shfl_xor(v, 4);
        v += __shfl_xor(v, 8);  v += __shfl_xor(v, 16); v += __shfl_xor(v, 32);
        if (lane == 0) part_s[chSel][ni] = v;
    }
    __syncthreads();
    if (tid < 32) {
        int node = base + tid;
        if (node < Nn) {
            float o = part_s[0][tid] + part_s[1][tid] + lb;
            o *= night[(long)node * 13 + t + 1];
            out[(long)node * 13 + t + 1] = o;
            if (t + 1 < Tt) {
                __half* xr = Xh + (long)node * 8;
                xr[0] = __float2half(o);
                #pragma unroll
                for (int c = 0; c < 4; c++)
                    xr[1 + c] = __float2half(env[(long)node * 48 + c * 12 + t + 1]);
            }
        }
    }
}

extern "C" void kernel_launch(void* const* d_in, const int* in_sizes, int n_in,
                              void* d_out, int out_size, void* d_ws, size_t ws_size,
                              hipStream_t stream) {
    const float* x      = (const float*)d_in[0];
    const float* env    = (const float*)d_in[1];
    const float* coords = (const float*)d_in[2];
    const int*   ei     = (const int*)d_in[3];
    const float* ew     = (const float*)d_in[4];
    const float* night  = (const float*)d_in[5];
    const float* Wz     = (const float*)d_in[6];
    const float* bz     = (const float*)d_in[7];
    // d_in[8]=Wr, d_in[9]=br unused (R gate never affects output)
    const float* Wh     = (const float*)d_in[10];
    const float* bh     = (const float*)d_in[11];
    const float* linW   = (const float*)d_in[12];
    const float* linb   = (const float*)d_in[13];
    float* out = (float*)d_out;

    float* w = (float*)d_ws;
    float* wzT     = w;                     // 36*128
    float* whT     = w + 4608;
    float* inv_out = w + 9216;              // N
    float* inv_in  = w + 59216;
    __half* Xh   = (__half*)(w + 109216);   // N x 8 halves (16B-aligned)
    __half* TxoH = (__half*)(w + 309216);
    __half* TxiH = (__half*)(w + 509216);
    int* ibase   = (int*)(w + 709216);
    int* cntR    = ibase;                   // N
    int* cntC    = ibase + 50000;
    int* startR  = ibase + 100000;          // N
    int* startC  = ibase + 150000;
    int* nextR   = ibase + 200000;          // N
    int* nextC   = ibase + 250000;
    int* bsum    = ibase + 300000;          // 2 x 256
    int* bbase   = ibase + 300512;
    unsigned* adjR = (unsigned*)(ibase + 301024);   // E x 4B
    unsigned* adjC = adjR + Ee;             // ends ibase + 1,901,024 (~10.4 MB)

    // ---- CSR build: r5's proven kernels ----
    hipMemsetAsync(cntR, 0, 2 * Nn * sizeof(int), stream);
    hist_kernel<<<(Ee + 255) / 256, 256, 0, stream>>>(ei, cntR, cntC);
    scanA_kernel<<<dim3(SCB, 2), 256, 0, stream>>>(cntR, cntC, bsum);
    scanB_kernel<<<2, 256, 0, stream>>>(bsum, bbase);
    scanC_kernel<<<dim3(SCB, 2), 256, 0, stream>>>(
        cntR, cntC, bbase, startR, startC, nextR, nextC);
    scatter_banded<<<8 * 256, 256, 0, stream>>>(ei, ew, nextR, nextC, adjR, adjC);

    weff_kernel<<<(2 * 36 * 128 + 255) / 256, 256, 0, stream>>>(Wz, Wh, bz, bh, wzT, whT);
    init_kernel<<<(Nn + 255) / 256, 256, 0, stream>>>(x, env, coords, Xh, out);

    for (int t = 0; t < Tt; t++) {
        gather1_kernel<<<(Nn * 8 + 255) / 256, 256, 0, stream>>>(
            startR, cntR, adjR, startC, cntC, adjC, Xh, TxoH, TxiH, inv_out, inv_in);
        step2_kernel<<<(Nn + 31) / 32, 256, 0, stream>>>(
            startR, cntR, adjR, startC, cntC, adjC, inv_out, inv_in,
            env, night, wzT, whT, linW, linb, Xh, TxoH, TxiH, out, t);
    }
}